// Round 18
// baseline (1153.672 us; speedup 1.0000x reference)
//
#include <hip/hip_runtime.h>
#include <hip/hip_bf16.h>
#include <math.h>

// Decoder: T=64, B=48, S=64, D=1024, E=300, V=32000
#define T_LEN 64
#define BATCH 48
#define SRC   64
#define DH    1024
#define EMB   300
#define EMBP  320    // EMB padded to multiple of 32 for MFMA
#define VOC   32000
#define GDIM  4096   // 4*DH
#define XDIM  1324   // DH+EMB
#define NBLK_L 64    // persistent LSTM blocks

typedef unsigned short u16;
typedef unsigned long long u64;
typedef __attribute__((ext_vector_type(8))) short bf16x8;
typedef __attribute__((ext_vector_type(4))) float f32x4;
typedef __attribute__((ext_vector_type(4))) unsigned u32x4;

__device__ inline u16 f2bf(float f) {
  unsigned u = __float_as_uint(f);
  unsigned r = u + 0x7FFFu + ((u >> 16) & 1u);   // RNE
  return (u16)(r >> 16);
}
__device__ inline unsigned pack2bf(float lo, float hi) {
  return (unsigned)f2bf(lo) | ((unsigned)f2bf(hi) << 16);
}

// ---------------------------------------------------------------------------
// Tall-skinny GEMM for M=48 (round-13 verified): C[48,N]=A[48,K]@W[N,K]^T
// ---------------------------------------------------------------------------
template<int ACT>
__global__ __launch_bounds__(256) void smallgemm_tn(
    const float* __restrict__ A, int lda,
    const float* __restrict__ W, int ldw,
    const float* __restrict__ bias0, const float* __restrict__ bias1,
    float* __restrict__ C, int ldc, int N, int K)
{
  const int wv = threadIdx.x >> 6;
  const int lane = threadIdx.x & 63;
  const int j = blockIdx.x * 4 + wv;
  const int kl = lane & 15;
  const int bl = lane >> 4;
  const float* wrow = W + (size_t)j * ldw;

  float acc[12];
#pragma unroll
  for (int i = 0; i < 12; ++i) acc[i] = 0.f;

  for (int k0 = 0; k0 < K; k0 += 64) {
    const float4 w4 = *reinterpret_cast<const float4*>(wrow + k0 + kl * 4);
#pragma unroll
    for (int bb = 0; bb < 12; ++bb) {
      const int b = bb * 4 + bl;
      const float4 a4 = *reinterpret_cast<const float4*>(A + (size_t)b * lda + k0 + kl * 4);
      acc[bb] += a4.x * w4.x + a4.y * w4.y + a4.z * w4.z + a4.w * w4.w;
    }
  }

  const float badd = (bias0 ? bias0[j] : 0.f) + (bias1 ? bias1[j] : 0.f);
#pragma unroll
  for (int bb = 0; bb < 12; ++bb) {
    float v = acc[bb];
    v += __shfl_xor(v, 1);
    v += __shfl_xor(v, 2);
    v += __shfl_xor(v, 4);
    v += __shfl_xor(v, 8);
    if (kl == 0) {
      const int b = bb * 4 + bl;
      float r = v + badd;
      if (ACT == 1) r = tanhf(r);
      C[(size_t)b * ldc + j] = r;
    }
  }
}

// ---------------------------------------------------------------------------
// LDS swizzle shared by MFMA GEMMs
// ---------------------------------------------------------------------------
__device__ inline int lds_idx(int row, int chunk) {
  return row * 32 + ((chunk ^ ((row >> 1) & 3)) << 3);   // u16 units
}

// ---------------------------------------------------------------------------
// Fallback bf16 MFMA GEMM (B fp32, converted at stage) -- round-6 verified.
// ---------------------------------------------------------------------------
__global__ __launch_bounds__(256) void gemm_bf16_mfma(
    const u16* __restrict__ A, const float* __restrict__ B,
    const float* __restrict__ bias, float* __restrict__ C, int M, int N, int K)
{
  __shared__ u16 As[128 * 32];
  __shared__ u16 Bs[128 * 32];
  const int tid = threadIdx.x;
  const int lane = tid & 63;
  const int wv = tid >> 6;
  const int wr = wv >> 1, wc = wv & 1;

  const int nmt = M >> 7;
  const int chunk_sz = (int)gridDim.x >> 3;
  const int bid = (int)blockIdx.x;
  const int wg = (bid & 7) * chunk_sz + (bid >> 3);
  const int bm = (wg % nmt) * 128;
  const int bn = (wg / nmt) * 128;

  const int srow = tid >> 1;
  const int c0 = (tid & 1) << 1;

  const u16*  Ap = A + (size_t)(bm + srow) * K + (c0 << 3);
  const float* Bp = B + (size_t)(bn + srow) * K + (c0 << 3);

  f32x4 acc[4][4];
#pragma unroll
  for (int i = 0; i < 4; ++i)
#pragma unroll
    for (int j = 0; j < 4; ++j) acc[i][j] = (f32x4){0.f, 0.f, 0.f, 0.f};

  f32x4 a0 = *(const f32x4*)(Ap);
  f32x4 a1 = *(const f32x4*)(Ap + 8);
  float4 q0 = *(const float4*)(Bp);
  float4 q1 = *(const float4*)(Bp + 4);
  float4 q2 = *(const float4*)(Bp + 8);
  float4 q3 = *(const float4*)(Bp + 12);

  for (int k0 = 0; k0 < K; k0 += 32) {
    *(f32x4*)(&As[lds_idx(srow, c0)]) = a0;
    *(f32x4*)(&As[lds_idx(srow, c0 + 1)]) = a1;
    uint4 w0, w1;
    w0.x = pack2bf(q0.x, q0.y); w0.y = pack2bf(q0.z, q0.w);
    w0.z = pack2bf(q1.x, q1.y); w0.w = pack2bf(q1.z, q1.w);
    w1.x = pack2bf(q2.x, q2.y); w1.y = pack2bf(q2.z, q2.w);
    w1.z = pack2bf(q3.x, q3.y); w1.w = pack2bf(q3.z, q3.w);
    *(uint4*)(&Bs[lds_idx(srow, c0)]) = w0;
    *(uint4*)(&Bs[lds_idx(srow, c0 + 1)]) = w1;
    __syncthreads();

    if (k0 + 32 < K) {
      a0 = *(const f32x4*)(Ap + k0 + 32);
      a1 = *(const f32x4*)(Ap + k0 + 40);
      q0 = *(const float4*)(Bp + k0 + 32);
      q1 = *(const float4*)(Bp + k0 + 36);
      q2 = *(const float4*)(Bp + k0 + 40);
      q3 = *(const float4*)(Bp + k0 + 44);
    }

    bf16x8 af[4], bfr[4];
#pragma unroll
    for (int mi = 0; mi < 4; ++mi)
      af[mi] = *(const bf16x8*)(&As[lds_idx(wr * 64 + mi * 16 + (lane & 15), lane >> 4)]);
#pragma unroll
    for (int ni = 0; ni < 4; ++ni)
      bfr[ni] = *(const bf16x8*)(&Bs[lds_idx(wc * 64 + ni * 16 + (lane & 15), lane >> 4)]);
#pragma unroll
    for (int mi = 0; mi < 4; ++mi)
#pragma unroll
      for (int ni = 0; ni < 4; ++ni)
        acc[mi][ni] = __builtin_amdgcn_mfma_f32_16x16x32_bf16(af[mi], bfr[ni], acc[mi][ni], 0, 0, 0);
    __syncthreads();
  }

  const int r0 = bm + wr * 64 + ((lane >> 4) << 2);
  const int cc0 = bn + wc * 64 + (lane & 15);
#pragma unroll
  for (int mi = 0; mi < 4; ++mi)
#pragma unroll
    for (int ni = 0; ni < 4; ++ni) {
      const int col = cc0 + ni * 16;
      const float bv = bias[col];
#pragma unroll
      for (int r = 0; r < 4; ++r)
        C[(size_t)(r0 + mi * 16 + r) * N + col] = acc[mi][ni][r] + bv;
    }
}

// ---------------------------------------------------------------------------
// bf16 x bf16 MFMA GEMM (round-13 verified structure) with optional
// bias / rowadd (row-periodic fp32 add, used to fold ctxpart into xg).
// ---------------------------------------------------------------------------
__global__ __launch_bounds__(256) void gemm_bb_mfma(
    const u16* __restrict__ A, const u16* __restrict__ B,
    const float* __restrict__ bias,
    const float* __restrict__ rowadd, int rowmod,
    float* __restrict__ C, int M, int N, int K)
{
  __shared__ u16 As[128 * 32];
  __shared__ u16 Bs[128 * 32];
  const int tid = threadIdx.x;
  const int lane = tid & 63;
  const int wv = tid >> 6;
  const int wr = wv >> 1, wc = wv & 1;

  const int nmt = M >> 7;
  const int chunk_sz = (int)gridDim.x >> 3;
  const int bid = (int)blockIdx.x;
  const int wg = (bid & 7) * chunk_sz + (bid >> 3);
  const int bm = (wg % nmt) * 128;
  const int bn = (wg / nmt) * 128;

  const int srow = tid >> 1;
  const int c0 = (tid & 1) << 1;

  const u16* Ap = A + (size_t)(bm + srow) * K + (c0 << 3);
  const u16* Bp = B + (size_t)(bn + srow) * K + (c0 << 3);

  f32x4 acc[4][4];
#pragma unroll
  for (int i = 0; i < 4; ++i)
#pragma unroll
    for (int j = 0; j < 4; ++j) acc[i][j] = (f32x4){0.f, 0.f, 0.f, 0.f};

  f32x4 a0 = *(const f32x4*)(Ap);
  f32x4 a1 = *(const f32x4*)(Ap + 8);
  f32x4 b0 = *(const f32x4*)(Bp);
  f32x4 b1 = *(const f32x4*)(Bp + 8);

  for (int k0 = 0; k0 < K; k0 += 32) {
    *(f32x4*)(&As[lds_idx(srow, c0)]) = a0;
    *(f32x4*)(&As[lds_idx(srow, c0 + 1)]) = a1;
    *(f32x4*)(&Bs[lds_idx(srow, c0)]) = b0;
    *(f32x4*)(&Bs[lds_idx(srow, c0 + 1)]) = b1;
    __syncthreads();

    if (k0 + 32 < K) {   // prefetch next tile (overlaps MFMA below)
      a0 = *(const f32x4*)(Ap + k0 + 32);
      a1 = *(const f32x4*)(Ap + k0 + 40);
      b0 = *(const f32x4*)(Bp + k0 + 32);
      b1 = *(const f32x4*)(Bp + k0 + 40);
    }

    bf16x8 af[4], bfr[4];
#pragma unroll
    for (int mi = 0; mi < 4; ++mi)
      af[mi] = *(const bf16x8*)(&As[lds_idx(wr * 64 + mi * 16 + (lane & 15), lane >> 4)]);
#pragma unroll
    for (int ni = 0; ni < 4; ++ni)
      bfr[ni] = *(const bf16x8*)(&Bs[lds_idx(wc * 64 + ni * 16 + (lane & 15), lane >> 4)]);
#pragma unroll
    for (int mi = 0; mi < 4; ++mi)
#pragma unroll
      for (int ni = 0; ni < 4; ++ni)
        acc[mi][ni] = __builtin_amdgcn_mfma_f32_16x16x32_bf16(af[mi], bfr[ni], acc[mi][ni], 0, 0, 0);
    __syncthreads();
  }

  const int r0 = bm + wr * 64 + ((lane >> 4) << 2);
  const int cc0 = bn + wc * 64 + (lane & 15);
#pragma unroll
  for (int mi = 0; mi < 4; ++mi)
#pragma unroll
    for (int ni = 0; ni < 4; ++ni) {
      const int col = cc0 + ni * 16;
      const float bv = bias ? bias[col] : 0.f;
#pragma unroll
      for (int r = 0; r < 4; ++r) {
        const int row = r0 + mi * 16 + r;
        float v = acc[mi][ni][r] + bv;
        if (rowadd) v += rowadd[(size_t)(row % rowmod) * N + col];
        C[(size_t)row * N + col] = v;
      }
    }
}

// ---------------------------------------------------------------------------
// gen_w fp32 -> bf16 (separate dispatch AFTER the LSTM -- alias-safe)
// ---------------------------------------------------------------------------
__global__ __launch_bounds__(256) void cvt_f32_bf16_kernel(
    const float* __restrict__ src, u16* __restrict__ dst, int n8)
{
  const int i = blockIdx.x * 256 + threadIdx.x;
  if (i >= n8) return;
  const float4 s0 = ((const float4*)src)[2 * i];
  const float4 s1 = ((const float4*)src)[2 * i + 1];
  uint4 w;
  w.x = pack2bf(s0.x, s0.y); w.y = pack2bf(s0.z, s0.w);
  w.z = pack2bf(s1.x, s1.y); w.w = pack2bf(s1.z, s1.w);
  ((uint4*)dst)[i] = w;
}

// ---------------------------------------------------------------------------
// Attention / misc small kernels
// ---------------------------------------------------------------------------
__global__ __launch_bounds__(64) void scores_kernel(
    const float* __restrict__ enc, const float* __restrict__ ht,
    float* __restrict__ sc)
{
  const int sb = blockIdx.x;
  const int b = sb % BATCH;
  const int lane = threadIdx.x;
  const float* e = enc + (size_t)sb * DH;
  const float* h = ht + (size_t)b * DH;
  float sum = 0.f;
  for (int k = lane * 4; k < DH; k += 64 * 4) {
    float4 ev = *reinterpret_cast<const float4*>(e + k);
    float4 hv = *reinterpret_cast<const float4*>(h + k);
    sum += ev.x * hv.x + ev.y * hv.y + ev.z * hv.z + ev.w * hv.w;
  }
#pragma unroll
  for (int off = 32; off; off >>= 1) sum += __shfl_down(sum, off);
  if (lane == 0) sc[sb] = sum;
}

__global__ __launch_bounds__(64) void logsoftmax_kernel(
    const float* __restrict__ sc, float* __restrict__ a)
{
  const int s = threadIdx.x;
  if (s >= SRC) return;
  const float* r = sc + (size_t)s * BATCH;
  float m = -INFINITY;
  for (int b = 0; b < BATCH; ++b) m = fmaxf(m, r[b]);
  float sum = 0.f;
  for (int b = 0; b < BATCH; ++b) sum += expf(r[b] - m);
  const float lse = m + logf(sum);
  float* o = a + (size_t)s * BATCH;
  for (int b = 0; b < BATCH; ++b) o[b] = r[b] - lse;
}

__global__ __launch_bounds__(256) void ctxsum_kernel(
    const float* __restrict__ a, const float* __restrict__ enc,
    const float* __restrict__ hidden, float* __restrict__ cat)
{
  const int b = blockIdx.x;
  const int d = blockIdx.y * 256 + threadIdx.x;
  float sum = 0.f;
  for (int s = 0; s < SRC; ++s)
    sum = fmaf(a[s * BATCH + b], enc[(size_t)(s * BATCH + b) * DH + d], sum);
  cat[(size_t)b * (2 * DH) + d] = sum;
  cat[(size_t)b * (2 * DH) + DH + d] = hidden[(size_t)b * DH + d];
}

// Embedding gather -> bf16, K padded 300->320 with zeros
__global__ __launch_bounds__(256) void gather_bf16_kernel(
    const int* __restrict__ targ, const float* __restrict__ emb,
    u16* __restrict__ embedded)
{
  const int tb = blockIdx.x;
  const int tok = targ[tb];
  const float* src = emb + (size_t)tok * EMB;
  u16* dst = embedded + (size_t)tb * EMBP;
  for (int j = threadIdx.x; j < EMBP; j += blockDim.x)
    dst[j] = (j < EMB) ? f2bf(src[j]) : (u16)0;
}

// Pack w_ih[:, 1024:1324] -> bf16 [GDIM][EMBP] zero-padded
__global__ __launch_bounds__(256) void pack_wih_kernel(
    const float* __restrict__ w_ih, u16* __restrict__ dst)
{
  const int n = blockIdx.x;
  const float* src = w_ih + (size_t)n * XDIM + DH;
  u16* d = dst + (size_t)n * EMBP;
  for (int j = threadIdx.x; j < EMBP; j += blockDim.x)
    d[j] = (j < EMB) ? f2bf(src[j]) : (u16)0;
}

// ---------------------------------------------------------------------------
__global__ __launch_bounds__(64) void pack_whh_kernel(
    const float* __restrict__ w_hh, u16* __restrict__ wpack)
{
  const int bid = blockIdx.x;           // 8192
  const int k0 = bid & 31;
  const int g = (bid >> 5) & 3;
  const int jt = bid >> 7;
  const int l = threadIdx.x;
  const int row = g * 1024 + jt * 16 + (l & 15);
  const int col = k0 * 32 + (l >> 4) * 8;
  const float* src = w_hh + (size_t)row * DH + col;
  u16* dst = wpack + ((size_t)bid * 64 + l) * 8;
  uint4 w;
  float4 s0 = *(const float4*)(src);
  float4 s1 = *(const float4*)(src + 4);
  w.x = pack2bf(s0.x, s0.y); w.y = pack2bf(s0.z, s0.w);
  w.z = pack2bf(s1.x, s1.y); w.w = pack2bf(s1.z, s1.w);
  *(uint4*)dst = w;
}

__global__ void init_bar_kernel(unsigned* bar) {
  if (threadIdx.x < 256) bar[threadIdx.x] = 0u;
}

// ---------------------------------------------------------------------------
// Persistent LSTM v7 -- v5 structure, flat-flag barrier.
// Arrive: after the post-act __syncthreads (which drains every wave's h
// stores to the coherence point), tid0 fire-and-forget stores flags[jt]=t+1
// (ONE round trip; replaces v5's serialized leaf->root RMW chain).
// Wait: wave 0 only polls all 64 flags with one coalesced sc-load + ballot
// (v6's regression came from all 12 waves polling).  Full-barrier-per-step
// semantics identical to v5 -> double-buffer skew invariant unchanged.
// ---------------------------------------------------------------------------
__global__ __launch_bounds__(768, 1) void lstm_persistent(
    const u16* __restrict__ wpack,      // [64][4][32][64][8]
    const float* __restrict__ xg,       // [T*48, 4096], ctx+biases folded
    unsigned* __restrict__ hbuf0,       // packed h as u32[3*32*64*4]
    unsigned* __restrict__ hbuf1,
    u16* __restrict__ hs,               // [T][48][1024] row-major
    unsigned* __restrict__ bar)         // flags at bar+64 (init 0)
{
  __shared__ float gate_s[4][48][16];
  __shared__ u16 h_lds[3 * 32 * 64 * 8];   // 96 KB, packed A-frag layout
  const int jt = (int)blockIdx.x;       // 0..63
  const int tid = (int)threadIdx.x;
  const int l = tid & 63;
  const int wv = tid >> 6;              // 0..11
  const int g = wv & 3;
  const int mi = wv >> 2;               // 0..2
  const int ab = tid >> 4;              // act: batch 0..47
  const int aj = tid & 15;              // act: j within tile
  const int ajj = jt * 16 + aj;
  float c_reg = 0.f;

  const u16* wp = wpack + (((size_t)(jt * 4 + g) * 32) * 64 + l) * 8;
  const int w_mi = ab >> 4, w_r = ab & 15;
  const int w_k0 = ajj >> 5, w_sub = (ajj & 31) >> 3, w_e = ajj & 7;
  const size_t w_off32 =
      (((size_t)((w_mi * 32 + w_k0) * 64) + w_sub * 16 + w_r) * 8 + w_e) >> 1;
  unsigned* const flags = bar + 64;

  size_t xb = (size_t)ab * GDIM + ajj;
  float p_i = xg[xb + 0 * DH];
  float p_f = xg[xb + 1 * DH];
  float p_g = xg[xb + 2 * DH];
  float p_o = xg[xb + 3 * DH];

  for (int t = 0; t < T_LEN; ++t) {
    if (t > 0) {
      // stage h(t-1): coherent coalesced loads (MALL) -> regs -> LDS
      const u32x4* src = (const u32x4*)((t & 1) ? hbuf0 : hbuf1) + (size_t)tid * 8;
      u32x4 v0, v1, v2, v3, v4, v5, v6, v7;
      asm volatile("global_load_dwordx4 %0, %1, off sc0 sc1" : "=v"(v0) : "v"(src + 0));
      asm volatile("global_load_dwordx4 %0, %1, off sc0 sc1" : "=v"(v1) : "v"(src + 1));
      asm volatile("global_load_dwordx4 %0, %1, off sc0 sc1" : "=v"(v2) : "v"(src + 2));
      asm volatile("global_load_dwordx4 %0, %1, off sc0 sc1" : "=v"(v3) : "v"(src + 3));
      asm volatile("global_load_dwordx4 %0, %1, off sc0 sc1" : "=v"(v4) : "v"(src + 4));
      asm volatile("global_load_dwordx4 %0, %1, off sc0 sc1" : "=v"(v5) : "v"(src + 5));
      asm volatile("global_load_dwordx4 %0, %1, off sc0 sc1" : "=v"(v6) : "v"(src + 6));
      asm volatile("global_load_dwordx4 %0, %1, off sc0 sc1" : "=v"(v7) : "v"(src + 7));
      asm volatile("s_waitcnt vmcnt(0)" ::: "memory");
      __builtin_amdgcn_sched_barrier(0);
      u32x4* dst = (u32x4*)h_lds + (size_t)tid * 8;
      dst[0] = v0; dst[1] = v1; dst[2] = v2; dst[3] = v3;
      dst[4] = v4; dst[5] = v5; dst[6] = v6; dst[7] = v7;
      __syncthreads();

      const u16* hpm = h_lds + ((size_t)(mi * 32) * 64 + l) * 8;
      f32x4 acc = {0.f, 0.f, 0.f, 0.f};
#pragma unroll 8
      for (int k0 = 0; k0 < 32; ++k0) {
        bf16x8 bfrag = *(const bf16x8*)(wp + (size_t)k0 * 512);
        bf16x8 afrag = *(const bf16x8*)(hpm + (size_t)k0 * 512);
        acc = __builtin_amdgcn_mfma_f32_16x16x32_bf16(afrag, bfrag, acc, 0, 0, 0);
      }
      const int rr = (l >> 4) << 2;
      const int cc = l & 15;
#pragma unroll
      for (int r = 0; r < 4; ++r)
        gate_s[g][mi * 16 + rr + r][cc] = acc[r];
    }
    __syncthreads();

    unsigned hpair = 0;
    {
      float gi = p_i, gf = p_f, gg = p_g, go = p_o;
      if (t > 0) {
        gi += gate_s[0][ab][aj];
        gf += gate_s[1][ab][aj];
        gg += gate_s[2][ab][aj];
        go += gate_s[3][ab][aj];
      }
      const float si = 1.f / (1.f + expf(-gi));
      const float sf = 1.f / (1.f + expf(-gf));
      const float so = 1.f / (1.f + expf(-go));
      const float tg = tanhf(gg);
      c_reg = sf * c_reg + si * tg;
      const float h = so * tanhf(c_reg);
      const unsigned hb = (unsigned)f2bf(h);
      const unsigned other = __shfl_xor(hb, 1);
      hpair = (aj & 1) ? 0u : (hb | (other << 16));
      if (!(aj & 1)) {
        unsigned* hw = (t & 1) ? hbuf1 : hbuf0;
        __hip_atomic_store(hw + w_off32, hpair, __ATOMIC_RELAXED,
                           __HIP_MEMORY_SCOPE_AGENT);
      }
    }

    // barrier arrival: h stores drained by syncthreads, then ONE flag store
    __syncthreads();
    const bool last = (t + 1 == T_LEN);
    if (tid == 0 && !last)
      __hip_atomic_store(flags + jt, (unsigned)(t + 1), __ATOMIC_RELAXED,
                         __HIP_MEMORY_SCOPE_AGENT);

    // overlapped with barrier latency: hs store + next-step xg prefetch
    if (!(aj & 1))
      ((unsigned*)hs)[((size_t)t * BATCH * DH + (size_t)ab * DH + ajj) >> 1] = hpair;
    if (!last) {
      xb = ((size_t)(t + 1) * BATCH + ab) * GDIM + ajj;
      p_i = xg[xb + 0 * DH];
      p_f = xg[xb + 1 * DH];
      p_g = xg[xb + 2 * DH];
      p_o = xg[xb + 3 * DH];

      // wait: wave 0 polls all 64 flags (one coalesced sc-load + ballot)
      if (tid < 64) {
        const unsigned target = (unsigned)(t + 1);
        while (true) {
          unsigned f;
          asm volatile("global_load_dword %0, %1, off sc0 sc1\n\t"
                       "s_waitcnt vmcnt(0)"
                       : "=v"(f) : "v"(flags + tid) : "memory");
          if (__ballot(f < target) == 0ull) break;
          __builtin_amdgcn_s_sleep(2);
        }
      }
      __syncthreads();
    }
  }
}

// ---------------------------------------------------------------------------
extern "C" void kernel_launch(void* const* d_in, const int* in_sizes, int n_in,
                              void* d_out, int out_size, void* d_ws, size_t ws_size,
                              hipStream_t stream) {
  const int*   targ     = (const int*)d_in[0];
  const float* enc      = (const float*)d_in[1];
  const float* emb      = (const float*)d_in[2];
  const float* attin_w  = (const float*)d_in[3];
  const float* attin_b  = (const float*)d_in[4];
  const float* attout_w = (const float*)d_in[5];
  const float* attout_b = (const float*)d_in[6];
  const float* gen_w    = (const float*)d_in[7];
  const float* gen_b    = (const float*)d_in[8];
  const float* hidden   = (const float*)d_in[9];
  const float* w_ih     = (const float*)d_in[10];
  const float* w_hh     = (const float*)d_in[11];
  const float* b_ih     = (const float*)d_in[12];
  const float* b_hh     = (const float*)d_in[13];
  float* out = (float*)d_out;

  char* wsp = (char*)d_ws;
  auto alloc = [&](size_t bytes) {
    char* p = wsp;
    wsp += (bytes + 255) & ~(size_t)255;
    return p;
  };
  // --- persistent region (alive through the final GEMM) ---
  u16*   hs_bf16  = (u16*)alloc((size_t)T_LEN * BATCH * DH * 2);
  unsigned* hbuf0 = (unsigned*)alloc((size_t)3 * 32 * 64 * 8 * 2);
  unsigned* hbuf1 = (unsigned*)alloc((size_t)3 * 32 * 64 * 8 * 2);
  unsigned* bar   = (unsigned*)alloc(2048);
  // --- transient pool (dead after lstm_persistent) ---
  char* pool = wsp;
  float* ht       = (float*)alloc((size_t)BATCH * DH * 4);
  float* sc       = (float*)alloc((size_t)SRC * BATCH * 4);
  float* attn     = (float*)alloc((size_t)SRC * BATCH * 4);
  float* cat      = (float*)alloc((size_t)BATCH * 2 * DH * 4);
  float* ctx      = (float*)alloc((size_t)BATCH * DH * 4);
  float* ctxpart  = (float*)alloc((size_t)BATCH * GDIM * 4);
  u16*   emb_bf16 = (u16*)alloc((size_t)T_LEN * BATCH * EMBP * 2);
  u16*   wih_bf16 = (u16*)alloc((size_t)GDIM * EMBP * 2);
  float* xg       = (float*)alloc((size_t)T_LEN * BATCH * GDIM * 4);
  u16*   wpack    = (u16*)alloc((size_t)GDIM * DH * 2);
  const size_t used_trans = (size_t)(wsp - (char*)d_ws);
  // genw_bf16 ALIASES the transient pool; written ONLY after the LSTM
  // completes (separate dispatch), when the whole pool is dead.
  u16* genw_bf16 = (u16*)pool;
  const size_t need_genw = (size_t)(pool - (char*)d_ws) + (size_t)VOC * DH * 2;
  const bool bigB = (need_genw <= ws_size) && (used_trans <= ws_size);

  // 0. weight reshapes
  pack_whh_kernel<<<64 * 4 * 32, 64, 0, stream>>>(w_hh, wpack);
  pack_wih_kernel<<<GDIM, 256, 0, stream>>>(w_ih, wih_bf16);

  // 1. ht = hidden @ attin_w^T + attin_b       [48,1024] (tall-skinny)
  smallgemm_tn<0><<<DH / 4, 256, 0, stream>>>(
      hidden, DH, attin_w, DH, attin_b, nullptr, ht, DH, DH, DH);

  // 2-4. scores, log_softmax(axis=batch), context sum
  scores_kernel<<<SRC * BATCH, 64, 0, stream>>>(enc, ht, sc);
  logsoftmax_kernel<<<1, 64, 0, stream>>>(sc, attn);
  ctxsum_kernel<<<dim3(BATCH, DH / 256), 256, 0, stream>>>(attn, enc, hidden, cat);

  // 5. context = tanh(cat @ attout_w^T + attout_b)   [48,1024]
  smallgemm_tn<1><<<DH / 4, 256, 0, stream>>>(
      cat, 2 * DH, attout_w, 2 * DH, attout_b, nullptr, ctx, DH, DH, 2 * DH);

  // 6. ctxpart = context @ w_ih[:, :1024]^T + b_ih + b_hh   [48,4096]
  smallgemm_tn<0><<<GDIM / 4, 256, 0, stream>>>(
      ctx, DH, w_ih, XDIM, b_ih, b_hh, ctxpart, GDIM, GDIM, DH);

  // 7. embedded = emb[targ] -> bf16, K padded to 320
  gather_bf16_kernel<<<T_LEN * BATCH, 256, 0, stream>>>(targ, emb, emb_bf16);

  // 8. xg = embedded @ w_ih[:,1024:]^T (+ ctxpart row-fold)  [3072,4096] MFMA
  gemm_bb_mfma<<<(T_LEN * BATCH / 128) * (GDIM / 128), 256, 0, stream>>>(
      emb_bf16, wih_bf16, nullptr, ctxpart, BATCH, xg,
      T_LEN * BATCH, GDIM, EMBP);

  // 9. persistent LSTM (v7, flat-flag barrier)
  init_bar_kernel<<<1, 256, 0, stream>>>(bar);
  lstm_persistent<<<NBLK_L, 768, 0, stream>>>(wpack, xg, hbuf0, hbuf1, hs_bf16, bar);

  // 10. cvt (AFTER LSTM -- pool dead, alias safe) + final GEMM
  if (bigB) {
    cvt_f32_bf16_kernel<<<(VOC * DH / 8 + 255) / 256, 256, 0, stream>>>(
        gen_w, genw_bf16, VOC * DH / 8);
    gemm_bb_mfma<<<(T_LEN * BATCH / 128) * (VOC / 128), 256, 0, stream>>>(
        hs_bf16, genw_bf16, gen_b, nullptr, 1, out, T_LEN * BATCH, VOC, DH);
  } else {
    gemm_bf16_mfma<<<(T_LEN * BATCH / 128) * (VOC / 128), 256, 0, stream>>>(
        hs_bf16, gen_w, gen_b, out, T_LEN * BATCH, VOC, DH);
  }
}

// Round 19
// 1129.947 us; speedup vs baseline: 1.0210x; 1.0210x over previous
//
#include <hip/hip_runtime.h>
#include <hip/hip_bf16.h>
#include <math.h>

// Decoder: T=64, B=48, S=64, D=1024, E=300, V=32000
#define T_LEN 64
#define BATCH 48
#define SRC   64
#define DH    1024
#define EMB   300
#define EMBP  320    // EMB padded to multiple of 32 for MFMA
#define VOC   32000
#define GDIM  4096   // 4*DH
#define XDIM  1324   // DH+EMB
#define NBLK_L 64    // persistent LSTM blocks

typedef unsigned short u16;
typedef unsigned long long u64;
typedef __attribute__((ext_vector_type(8))) short bf16x8;
typedef __attribute__((ext_vector_type(4))) float f32x4;
typedef __attribute__((ext_vector_type(4))) unsigned u32x4;

__device__ inline u16 f2bf(float f) {
  unsigned u = __float_as_uint(f);
  unsigned r = u + 0x7FFFu + ((u >> 16) & 1u);   // RNE
  return (u16)(r >> 16);
}
__device__ inline unsigned pack2bf(float lo, float hi) {
  return (unsigned)f2bf(lo) | ((unsigned)f2bf(hi) << 16);
}

// ---------------------------------------------------------------------------
// Tall-skinny GEMM for M=48 (round-13 verified): C[48,N]=A[48,K]@W[N,K]^T
// ---------------------------------------------------------------------------
template<int ACT>
__global__ __launch_bounds__(256) void smallgemm_tn(
    const float* __restrict__ A, int lda,
    const float* __restrict__ W, int ldw,
    const float* __restrict__ bias0, const float* __restrict__ bias1,
    float* __restrict__ C, int ldc, int N, int K)
{
  const int wv = threadIdx.x >> 6;
  const int lane = threadIdx.x & 63;
  const int j = blockIdx.x * 4 + wv;
  const int kl = lane & 15;
  const int bl = lane >> 4;
  const float* wrow = W + (size_t)j * ldw;

  float acc[12];
#pragma unroll
  for (int i = 0; i < 12; ++i) acc[i] = 0.f;

  for (int k0 = 0; k0 < K; k0 += 64) {
    const float4 w4 = *reinterpret_cast<const float4*>(wrow + k0 + kl * 4);
#pragma unroll
    for (int bb = 0; bb < 12; ++bb) {
      const int b = bb * 4 + bl;
      const float4 a4 = *reinterpret_cast<const float4*>(A + (size_t)b * lda + k0 + kl * 4);
      acc[bb] += a4.x * w4.x + a4.y * w4.y + a4.z * w4.z + a4.w * w4.w;
    }
  }

  const float badd = (bias0 ? bias0[j] : 0.f) + (bias1 ? bias1[j] : 0.f);
#pragma unroll
  for (int bb = 0; bb < 12; ++bb) {
    float v = acc[bb];
    v += __shfl_xor(v, 1);
    v += __shfl_xor(v, 2);
    v += __shfl_xor(v, 4);
    v += __shfl_xor(v, 8);
    if (kl == 0) {
      const int b = bb * 4 + bl;
      float r = v + badd;
      if (ACT == 1) r = tanhf(r);
      C[(size_t)b * ldc + j] = r;
    }
  }
}

// ---------------------------------------------------------------------------
// LDS swizzle shared by MFMA GEMMs
// ---------------------------------------------------------------------------
__device__ inline int lds_idx(int row, int chunk) {
  return row * 32 + ((chunk ^ ((row >> 1) & 3)) << 3);   // u16 units
}

// ---------------------------------------------------------------------------
// Fallback bf16 MFMA GEMM (B fp32, converted at stage) -- round-6 verified.
// ---------------------------------------------------------------------------
__global__ __launch_bounds__(256) void gemm_bf16_mfma(
    const u16* __restrict__ A, const float* __restrict__ B,
    const float* __restrict__ bias, float* __restrict__ C, int M, int N, int K)
{
  __shared__ u16 As[128 * 32];
  __shared__ u16 Bs[128 * 32];
  const int tid = threadIdx.x;
  const int lane = tid & 63;
  const int wv = tid >> 6;
  const int wr = wv >> 1, wc = wv & 1;

  const int nmt = M >> 7;
  const int chunk_sz = (int)gridDim.x >> 3;
  const int bid = (int)blockIdx.x;
  const int wg = (bid & 7) * chunk_sz + (bid >> 3);
  const int bm = (wg % nmt) * 128;
  const int bn = (wg / nmt) * 128;

  const int srow = tid >> 1;
  const int c0 = (tid & 1) << 1;

  const u16*  Ap = A + (size_t)(bm + srow) * K + (c0 << 3);
  const float* Bp = B + (size_t)(bn + srow) * K + (c0 << 3);

  f32x4 acc[4][4];
#pragma unroll
  for (int i = 0; i < 4; ++i)
#pragma unroll
    for (int j = 0; j < 4; ++j) acc[i][j] = (f32x4){0.f, 0.f, 0.f, 0.f};

  f32x4 a0 = *(const f32x4*)(Ap);
  f32x4 a1 = *(const f32x4*)(Ap + 8);
  float4 q0 = *(const float4*)(Bp);
  float4 q1 = *(const float4*)(Bp + 4);
  float4 q2 = *(const float4*)(Bp + 8);
  float4 q3 = *(const float4*)(Bp + 12);

  for (int k0 = 0; k0 < K; k0 += 32) {
    *(f32x4*)(&As[lds_idx(srow, c0)]) = a0;
    *(f32x4*)(&As[lds_idx(srow, c0 + 1)]) = a1;
    uint4 w0, w1;
    w0.x = pack2bf(q0.x, q0.y); w0.y = pack2bf(q0.z, q0.w);
    w0.z = pack2bf(q1.x, q1.y); w0.w = pack2bf(q1.z, q1.w);
    w1.x = pack2bf(q2.x, q2.y); w1.y = pack2bf(q2.z, q2.w);
    w1.z = pack2bf(q3.x, q3.y); w1.w = pack2bf(q3.z, q3.w);
    *(uint4*)(&Bs[lds_idx(srow, c0)]) = w0;
    *(uint4*)(&Bs[lds_idx(srow, c0 + 1)]) = w1;
    __syncthreads();

    if (k0 + 32 < K) {
      a0 = *(const f32x4*)(Ap + k0 + 32);
      a1 = *(const f32x4*)(Ap + k0 + 40);
      q0 = *(const float4*)(Bp + k0 + 32);
      q1 = *(const float4*)(Bp + k0 + 36);
      q2 = *(const float4*)(Bp + k0 + 40);
      q3 = *(const float4*)(Bp + k0 + 44);
    }

    bf16x8 af[4], bfr[4];
#pragma unroll
    for (int mi = 0; mi < 4; ++mi)
      af[mi] = *(const bf16x8*)(&As[lds_idx(wr * 64 + mi * 16 + (lane & 15), lane >> 4)]);
#pragma unroll
    for (int ni = 0; ni < 4; ++ni)
      bfr[ni] = *(const bf16x8*)(&Bs[lds_idx(wc * 64 + ni * 16 + (lane & 15), lane >> 4)]);
#pragma unroll
    for (int mi = 0; mi < 4; ++mi)
#pragma unroll
      for (int ni = 0; ni < 4; ++ni)
        acc[mi][ni] = __builtin_amdgcn_mfma_f32_16x16x32_bf16(af[mi], bfr[ni], acc[mi][ni], 0, 0, 0);
    __syncthreads();
  }

  const int r0 = bm + wr * 64 + ((lane >> 4) << 2);
  const int cc0 = bn + wc * 64 + (lane & 15);
#pragma unroll
  for (int mi = 0; mi < 4; ++mi)
#pragma unroll
    for (int ni = 0; ni < 4; ++ni) {
      const int col = cc0 + ni * 16;
      const float bv = bias[col];
#pragma unroll
      for (int r = 0; r < 4; ++r)
        C[(size_t)(r0 + mi * 16 + r) * N + col] = acc[mi][ni][r] + bv;
    }
}

// ---------------------------------------------------------------------------
// bf16 x bf16 MFMA GEMM (round-13 verified structure) with optional
// bias / rowadd (row-periodic fp32 add, used to fold ctxpart into xg).
// ---------------------------------------------------------------------------
__global__ __launch_bounds__(256) void gemm_bb_mfma(
    const u16* __restrict__ A, const u16* __restrict__ B,
    const float* __restrict__ bias,
    const float* __restrict__ rowadd, int rowmod,
    float* __restrict__ C, int M, int N, int K)
{
  __shared__ u16 As[128 * 32];
  __shared__ u16 Bs[128 * 32];
  const int tid = threadIdx.x;
  const int lane = tid & 63;
  const int wv = tid >> 6;
  const int wr = wv >> 1, wc = wv & 1;

  const int nmt = M >> 7;
  const int chunk_sz = (int)gridDim.x >> 3;
  const int bid = (int)blockIdx.x;
  const int wg = (bid & 7) * chunk_sz + (bid >> 3);
  const int bm = (wg % nmt) * 128;
  const int bn = (wg / nmt) * 128;

  const int srow = tid >> 1;
  const int c0 = (tid & 1) << 1;

  const u16* Ap = A + (size_t)(bm + srow) * K + (c0 << 3);
  const u16* Bp = B + (size_t)(bn + srow) * K + (c0 << 3);

  f32x4 acc[4][4];
#pragma unroll
  for (int i = 0; i < 4; ++i)
#pragma unroll
    for (int j = 0; j < 4; ++j) acc[i][j] = (f32x4){0.f, 0.f, 0.f, 0.f};

  f32x4 a0 = *(const f32x4*)(Ap);
  f32x4 a1 = *(const f32x4*)(Ap + 8);
  f32x4 b0 = *(const f32x4*)(Bp);
  f32x4 b1 = *(const f32x4*)(Bp + 8);

  for (int k0 = 0; k0 < K; k0 += 32) {
    *(f32x4*)(&As[lds_idx(srow, c0)]) = a0;
    *(f32x4*)(&As[lds_idx(srow, c0 + 1)]) = a1;
    *(f32x4*)(&Bs[lds_idx(srow, c0)]) = b0;
    *(f32x4*)(&Bs[lds_idx(srow, c0 + 1)]) = b1;
    __syncthreads();

    if (k0 + 32 < K) {   // prefetch next tile (overlaps MFMA below)
      a0 = *(const f32x4*)(Ap + k0 + 32);
      a1 = *(const f32x4*)(Ap + k0 + 40);
      b0 = *(const f32x4*)(Bp + k0 + 32);
      b1 = *(const f32x4*)(Bp + k0 + 40);
    }

    bf16x8 af[4], bfr[4];
#pragma unroll
    for (int mi = 0; mi < 4; ++mi)
      af[mi] = *(const bf16x8*)(&As[lds_idx(wr * 64 + mi * 16 + (lane & 15), lane >> 4)]);
#pragma unroll
    for (int ni = 0; ni < 4; ++ni)
      bfr[ni] = *(const bf16x8*)(&Bs[lds_idx(wc * 64 + ni * 16 + (lane & 15), lane >> 4)]);
#pragma unroll
    for (int mi = 0; mi < 4; ++mi)
#pragma unroll
      for (int ni = 0; ni < 4; ++ni)
        acc[mi][ni] = __builtin_amdgcn_mfma_f32_16x16x32_bf16(af[mi], bfr[ni], acc[mi][ni], 0, 0, 0);
    __syncthreads();
  }

  const int r0 = bm + wr * 64 + ((lane >> 4) << 2);
  const int cc0 = bn + wc * 64 + (lane & 15);
#pragma unroll
  for (int mi = 0; mi < 4; ++mi)
#pragma unroll
    for (int ni = 0; ni < 4; ++ni) {
      const int col = cc0 + ni * 16;
      const float bv = bias ? bias[col] : 0.f;
#pragma unroll
      for (int r = 0; r < 4; ++r) {
        const int row = r0 + mi * 16 + r;
        float v = acc[mi][ni][r] + bv;
        if (rowadd) v += rowadd[(size_t)(row % rowmod) * N + col];
        C[(size_t)row * N + col] = v;
      }
    }
}

// ---------------------------------------------------------------------------
// gen_w fp32 -> bf16 (separate dispatch AFTER the LSTM -- alias-safe)
// ---------------------------------------------------------------------------
__global__ __launch_bounds__(256) void cvt_f32_bf16_kernel(
    const float* __restrict__ src, u16* __restrict__ dst, int n8)
{
  const int i = blockIdx.x * 256 + threadIdx.x;
  if (i >= n8) return;
  const float4 s0 = ((const float4*)src)[2 * i];
  const float4 s1 = ((const float4*)src)[2 * i + 1];
  uint4 w;
  w.x = pack2bf(s0.x, s0.y); w.y = pack2bf(s0.z, s0.w);
  w.z = pack2bf(s1.x, s1.y); w.w = pack2bf(s1.z, s1.w);
  ((uint4*)dst)[i] = w;
}

// ---------------------------------------------------------------------------
// Attention / misc small kernels
// ---------------------------------------------------------------------------
__global__ __launch_bounds__(64) void scores_kernel(
    const float* __restrict__ enc, const float* __restrict__ ht,
    float* __restrict__ sc)
{
  const int sb = blockIdx.x;
  const int b = sb % BATCH;
  const int lane = threadIdx.x;
  const float* e = enc + (size_t)sb * DH;
  const float* h = ht + (size_t)b * DH;
  float sum = 0.f;
  for (int k = lane * 4; k < DH; k += 64 * 4) {
    float4 ev = *reinterpret_cast<const float4*>(e + k);
    float4 hv = *reinterpret_cast<const float4*>(h + k);
    sum += ev.x * hv.x + ev.y * hv.y + ev.z * hv.z + ev.w * hv.w;
  }
#pragma unroll
  for (int off = 32; off; off >>= 1) sum += __shfl_down(sum, off);
  if (lane == 0) sc[sb] = sum;
}

__global__ __launch_bounds__(64) void logsoftmax_kernel(
    const float* __restrict__ sc, float* __restrict__ a)
{
  const int s = threadIdx.x;
  if (s >= SRC) return;
  const float* r = sc + (size_t)s * BATCH;
  float m = -INFINITY;
  for (int b = 0; b < BATCH; ++b) m = fmaxf(m, r[b]);
  float sum = 0.f;
  for (int b = 0; b < BATCH; ++b) sum += expf(r[b] - m);
  const float lse = m + logf(sum);
  float* o = a + (size_t)s * BATCH;
  for (int b = 0; b < BATCH; ++b) o[b] = r[b] - lse;
}

__global__ __launch_bounds__(256) void ctxsum_kernel(
    const float* __restrict__ a, const float* __restrict__ enc,
    const float* __restrict__ hidden, float* __restrict__ cat)
{
  const int b = blockIdx.x;
  const int d = blockIdx.y * 256 + threadIdx.x;
  float sum = 0.f;
  for (int s = 0; s < SRC; ++s)
    sum = fmaf(a[s * BATCH + b], enc[(size_t)(s * BATCH + b) * DH + d], sum);
  cat[(size_t)b * (2 * DH) + d] = sum;
  cat[(size_t)b * (2 * DH) + DH + d] = hidden[(size_t)b * DH + d];
}

// Embedding gather -> bf16, K padded 300->320 with zeros
__global__ __launch_bounds__(256) void gather_bf16_kernel(
    const int* __restrict__ targ, const float* __restrict__ emb,
    u16* __restrict__ embedded)
{
  const int tb = blockIdx.x;
  const int tok = targ[tb];
  const float* src = emb + (size_t)tok * EMB;
  u16* dst = embedded + (size_t)tb * EMBP;
  for (int j = threadIdx.x; j < EMBP; j += blockDim.x)
    dst[j] = (j < EMB) ? f2bf(src[j]) : (u16)0;
}

// Pack w_ih[:, 1024:1324] -> bf16 [GDIM][EMBP] zero-padded
__global__ __launch_bounds__(256) void pack_wih_kernel(
    const float* __restrict__ w_ih, u16* __restrict__ dst)
{
  const int n = blockIdx.x;
  const float* src = w_ih + (size_t)n * XDIM + DH;
  u16* d = dst + (size_t)n * EMBP;
  for (int j = threadIdx.x; j < EMBP; j += blockDim.x)
    d[j] = (j < EMB) ? f2bf(src[j]) : (u16)0;
}

// ---------------------------------------------------------------------------
__global__ __launch_bounds__(64) void pack_whh_kernel(
    const float* __restrict__ w_hh, u16* __restrict__ wpack)
{
  const int bid = blockIdx.x;           // 8192
  const int k0 = bid & 31;
  const int g = (bid >> 5) & 3;
  const int jt = bid >> 7;
  const int l = threadIdx.x;
  const int row = g * 1024 + jt * 16 + (l & 15);
  const int col = k0 * 32 + (l >> 4) * 8;
  const float* src = w_hh + (size_t)row * DH + col;
  u16* dst = wpack + ((size_t)bid * 64 + l) * 8;
  uint4 w;
  float4 s0 = *(const float4*)(src);
  float4 s1 = *(const float4*)(src + 4);
  w.x = pack2bf(s0.x, s0.y); w.y = pack2bf(s0.z, s0.w);
  w.z = pack2bf(s1.x, s1.y); w.w = pack2bf(s1.z, s1.w);
  *(uint4*)dst = w;
}

__global__ void init_bar_kernel(unsigned* bar) {
  if (threadIdx.x < 256) bar[threadIdx.x] = 0u;
}

// ---------------------------------------------------------------------------
// Persistent LSTM v5 (rounds 12/13/15/17 verified @ ~598us) -- best of six
// sync designs.  h staged via coalesced system-coherent vector loads;
// fence-free tree barrier (8 leaves + root); arrive-early/wait-late with
// hs store and xg prefetch overlapped.
// ---------------------------------------------------------------------------
__global__ __launch_bounds__(768, 1) void lstm_persistent(
    const u16* __restrict__ wpack,      // [64][4][32][64][8]
    const float* __restrict__ xg,       // [T*48, 4096], ctx+biases folded
    unsigned* __restrict__ hbuf0,       // packed h as u32[3*32*64*4]
    unsigned* __restrict__ hbuf1,
    u16* __restrict__ hs,               // [T][48][1024] row-major
    unsigned* __restrict__ bar)         // [0]=root, [16+16x]=leaf x
{
  __shared__ float gate_s[4][48][16];
  __shared__ u16 h_lds[3 * 32 * 64 * 8];   // 96 KB, packed A-frag layout
  const int jt = (int)blockIdx.x;       // 0..63
  const int tid = (int)threadIdx.x;
  const int l = tid & 63;
  const int wv = tid >> 6;              // 0..11
  const int g = wv & 3;
  const int mi = wv >> 2;               // 0..2
  const int ab = tid >> 4;              // act: batch 0..47
  const int aj = tid & 15;              // act: j within tile
  const int ajj = jt * 16 + aj;
  float c_reg = 0.f;

  const u16* wp = wpack + (((size_t)(jt * 4 + g) * 32) * 64 + l) * 8;
  const int w_mi = ab >> 4, w_r = ab & 15;
  const int w_k0 = ajj >> 5, w_sub = (ajj & 31) >> 3, w_e = ajj & 7;
  const size_t w_off32 =
      (((size_t)((w_mi * 32 + w_k0) * 64) + w_sub * 16 + w_r) * 8 + w_e) >> 1;
  unsigned* const leaf = bar + 16 + 16 * (jt & 7);
  unsigned* const root = bar;

  size_t xb = (size_t)ab * GDIM + ajj;
  float p_i = xg[xb + 0 * DH];
  float p_f = xg[xb + 1 * DH];
  float p_g = xg[xb + 2 * DH];
  float p_o = xg[xb + 3 * DH];

  for (int t = 0; t < T_LEN; ++t) {
    if (t > 0) {
      // stage h(t-1): coherent coalesced loads (MALL) -> regs -> LDS
      const u32x4* src = (const u32x4*)((t & 1) ? hbuf0 : hbuf1) + (size_t)tid * 8;
      u32x4 v0, v1, v2, v3, v4, v5, v6, v7;
      asm volatile("global_load_dwordx4 %0, %1, off sc0 sc1" : "=v"(v0) : "v"(src + 0));
      asm volatile("global_load_dwordx4 %0, %1, off sc0 sc1" : "=v"(v1) : "v"(src + 1));
      asm volatile("global_load_dwordx4 %0, %1, off sc0 sc1" : "=v"(v2) : "v"(src + 2));
      asm volatile("global_load_dwordx4 %0, %1, off sc0 sc1" : "=v"(v3) : "v"(src + 3));
      asm volatile("global_load_dwordx4 %0, %1, off sc0 sc1" : "=v"(v4) : "v"(src + 4));
      asm volatile("global_load_dwordx4 %0, %1, off sc0 sc1" : "=v"(v5) : "v"(src + 5));
      asm volatile("global_load_dwordx4 %0, %1, off sc0 sc1" : "=v"(v6) : "v"(src + 6));
      asm volatile("global_load_dwordx4 %0, %1, off sc0 sc1" : "=v"(v7) : "v"(src + 7));
      asm volatile("s_waitcnt vmcnt(0)" ::: "memory");
      __builtin_amdgcn_sched_barrier(0);
      u32x4* dst = (u32x4*)h_lds + (size_t)tid * 8;
      dst[0] = v0; dst[1] = v1; dst[2] = v2; dst[3] = v3;
      dst[4] = v4; dst[5] = v5; dst[6] = v6; dst[7] = v7;
      __syncthreads();

      const u16* hpm = h_lds + ((size_t)(mi * 32) * 64 + l) * 8;
      f32x4 acc = {0.f, 0.f, 0.f, 0.f};
#pragma unroll 8
      for (int k0 = 0; k0 < 32; ++k0) {
        bf16x8 bfrag = *(const bf16x8*)(wp + (size_t)k0 * 512);
        bf16x8 afrag = *(const bf16x8*)(hpm + (size_t)k0 * 512);
        acc = __builtin_amdgcn_mfma_f32_16x16x32_bf16(afrag, bfrag, acc, 0, 0, 0);
      }
      const int rr = (l >> 4) << 2;
      const int cc = l & 15;
#pragma unroll
      for (int r = 0; r < 4; ++r)
        gate_s[g][mi * 16 + rr + r][cc] = acc[r];
    }
    __syncthreads();

    unsigned hpair = 0;
    {
      float gi = p_i, gf = p_f, gg = p_g, go = p_o;
      if (t > 0) {
        gi += gate_s[0][ab][aj];
        gf += gate_s[1][ab][aj];
        gg += gate_s[2][ab][aj];
        go += gate_s[3][ab][aj];
      }
      const float si = 1.f / (1.f + expf(-gi));
      const float sf = 1.f / (1.f + expf(-gf));
      const float so = 1.f / (1.f + expf(-go));
      const float tg = tanhf(gg);
      c_reg = sf * c_reg + si * tg;
      const float h = so * tanhf(c_reg);
      const unsigned hb = (unsigned)f2bf(h);
      const unsigned other = __shfl_xor(hb, 1);
      hpair = (aj & 1) ? 0u : (hb | (other << 16));
      if (!(aj & 1)) {
        unsigned* hw = (t & 1) ? hbuf1 : hbuf0;
        __hip_atomic_store(hw + w_off32, hpair, __ATOMIC_RELAXED,
                           __HIP_MEMORY_SCOPE_AGENT);
      }
    }

    __syncthreads();
    const bool last = (t + 1 == T_LEN);
    if (tid == 0 && !last) {
      const unsigned pos =
          __hip_atomic_fetch_add(leaf, 1u, __ATOMIC_RELAXED, __HIP_MEMORY_SCOPE_AGENT);
      if ((pos & 7u) == 7u)
        __hip_atomic_fetch_add(root, 1u, __ATOMIC_RELAXED, __HIP_MEMORY_SCOPE_AGENT);
    }

    if (!(aj & 1))
      ((unsigned*)hs)[((size_t)t * BATCH * DH + (size_t)ab * DH + ajj) >> 1] = hpair;
    if (!last) {
      xb = ((size_t)(t + 1) * BATCH + ab) * GDIM + ajj;
      p_i = xg[xb + 0 * DH];
      p_f = xg[xb + 1 * DH];
      p_g = xg[xb + 2 * DH];
      p_o = xg[xb + 3 * DH];

      if (tid == 0) {
        const unsigned target = 8u * (unsigned)(t + 1);
        while (__hip_atomic_load(root, __ATOMIC_RELAXED, __HIP_MEMORY_SCOPE_AGENT) < target)
          __builtin_amdgcn_s_sleep(8);
      }
      __syncthreads();
    }
  }
}

// ---------------------------------------------------------------------------
extern "C" void kernel_launch(void* const* d_in, const int* in_sizes, int n_in,
                              void* d_out, int out_size, void* d_ws, size_t ws_size,
                              hipStream_t stream) {
  const int*   targ     = (const int*)d_in[0];
  const float* enc      = (const float*)d_in[1];
  const float* emb      = (const float*)d_in[2];
  const float* attin_w  = (const float*)d_in[3];
  const float* attin_b  = (const float*)d_in[4];
  const float* attout_w = (const float*)d_in[5];
  const float* attout_b = (const float*)d_in[6];
  const float* gen_w    = (const float*)d_in[7];
  const float* gen_b    = (const float*)d_in[8];
  const float* hidden   = (const float*)d_in[9];
  const float* w_ih     = (const float*)d_in[10];
  const float* w_hh     = (const float*)d_in[11];
  const float* b_ih     = (const float*)d_in[12];
  const float* b_hh     = (const float*)d_in[13];
  float* out = (float*)d_out;

  char* wsp = (char*)d_ws;
  auto alloc = [&](size_t bytes) {
    char* p = wsp;
    wsp += (bytes + 255) & ~(size_t)255;
    return p;
  };
  // --- persistent region (alive through the final GEMM) ---
  u16*   hs_bf16  = (u16*)alloc((size_t)T_LEN * BATCH * DH * 2);
  unsigned* hbuf0 = (unsigned*)alloc((size_t)3 * 32 * 64 * 8 * 2);
  unsigned* hbuf1 = (unsigned*)alloc((size_t)3 * 32 * 64 * 8 * 2);
  unsigned* bar   = (unsigned*)alloc(2048);
  // --- transient pool (dead after lstm_persistent) ---
  char* pool = wsp;
  float* ht       = (float*)alloc((size_t)BATCH * DH * 4);
  float* sc       = (float*)alloc((size_t)SRC * BATCH * 4);
  float* attn     = (float*)alloc((size_t)SRC * BATCH * 4);
  float* cat      = (float*)alloc((size_t)BATCH * 2 * DH * 4);
  float* ctx      = (float*)alloc((size_t)BATCH * DH * 4);
  float* ctxpart  = (float*)alloc((size_t)BATCH * GDIM * 4);
  u16*   emb_bf16 = (u16*)alloc((size_t)T_LEN * BATCH * EMBP * 2);
  u16*   wih_bf16 = (u16*)alloc((size_t)GDIM * EMBP * 2);
  float* xg       = (float*)alloc((size_t)T_LEN * BATCH * GDIM * 4);
  u16*   wpack    = (u16*)alloc((size_t)GDIM * DH * 2);
  const size_t used_trans = (size_t)(wsp - (char*)d_ws);
  // genw_bf16 ALIASES the transient pool; written ONLY after the LSTM
  // completes (separate dispatch), when the whole pool is dead.
  u16* genw_bf16 = (u16*)pool;
  const size_t need_genw = (size_t)(pool - (char*)d_ws) + (size_t)VOC * DH * 2;
  const bool bigB = (need_genw <= ws_size) && (used_trans <= ws_size);

  // 0. weight reshapes
  pack_whh_kernel<<<64 * 4 * 32, 64, 0, stream>>>(w_hh, wpack);
  pack_wih_kernel<<<GDIM, 256, 0, stream>>>(w_ih, wih_bf16);

  // 1. ht = hidden @ attin_w^T + attin_b       [48,1024] (tall-skinny)
  smallgemm_tn<0><<<DH / 4, 256, 0, stream>>>(
      hidden, DH, attin_w, DH, attin_b, nullptr, ht, DH, DH, DH);

  // 2-4. scores, log_softmax(axis=batch), context sum
  scores_kernel<<<SRC * BATCH, 64, 0, stream>>>(enc, ht, sc);
  logsoftmax_kernel<<<1, 64, 0, stream>>>(sc, attn);
  ctxsum_kernel<<<dim3(BATCH, DH / 256), 256, 0, stream>>>(attn, enc, hidden, cat);

  // 5. context = tanh(cat @ attout_w^T + attout_b)   [48,1024]
  smallgemm_tn<1><<<DH / 4, 256, 0, stream>>>(
      cat, 2 * DH, attout_w, 2 * DH, attout_b, nullptr, ctx, DH, DH, 2 * DH);

  // 6. ctxpart = context @ w_ih[:, :1024]^T + b_ih + b_hh   [48,4096]
  smallgemm_tn<0><<<GDIM / 4, 256, 0, stream>>>(
      ctx, DH, w_ih, XDIM, b_ih, b_hh, ctxpart, GDIM, GDIM, DH);

  // 7. embedded = emb[targ] -> bf16, K padded to 320
  gather_bf16_kernel<<<T_LEN * BATCH, 256, 0, stream>>>(targ, emb, emb_bf16);

  // 8. xg = embedded @ w_ih[:,1024:]^T (+ ctxpart row-fold)  [3072,4096] MFMA
  gemm_bb_mfma<<<(T_LEN * BATCH / 128) * (GDIM / 128), 256, 0, stream>>>(
      emb_bf16, wih_bf16, nullptr, ctxpart, BATCH, xg,
      T_LEN * BATCH, GDIM, EMBP);

  // 9. persistent LSTM (v5, tree barrier -- best of six sync designs)
  init_bar_kernel<<<1, 256, 0, stream>>>(bar);
  lstm_persistent<<<NBLK_L, 768, 0, stream>>>(wpack, xg, hbuf0, hbuf1, hs_bf16, bar);

  // 10. cvt (AFTER LSTM -- pool dead, alias safe) + final GEMM
  if (bigB) {
    cvt_f32_bf16_kernel<<<(VOC * DH / 8 + 255) / 256, 256, 0, stream>>>(
        gen_w, genw_bf16, VOC * DH / 8);
    gemm_bb_mfma<<<(T_LEN * BATCH / 128) * (VOC / 128), 256, 0, stream>>>(
        hs_bf16, genw_bf16, gen_b, nullptr, 1, out, T_LEN * BATCH, VOC, DH);
  } else {
    gemm_bf16_mfma<<<(T_LEN * BATCH / 128) * (VOC / 128), 256, 0, stream>>>(
        hs_bf16, gen_w, gen_b, out, T_LEN * BATCH, VOC, DH);
  }
}